// Round 1
// 224.174 us; speedup vs baseline: 1.0771x; 1.0771x over previous
//
#include <hip/hip_runtime.h>

typedef _Float16 f16;
typedef _Float16 f16x8 __attribute__((ext_vector_type(8)));
typedef _Float16 f16x4 __attribute__((ext_vector_type(4)));
typedef float f32x4 __attribute__((ext_vector_type(4)));

#define MFMA32(a, b, c) __builtin_amdgcn_mfma_f32_16x16x32_f16((a), (b), (c), 0, 0, 0)

constexpr int Bs = 2, Ls = 2048, DIM = 1024, NH = 16, HD = 64;
constexpr int BL = Bs * Ls;  // 4096
constexpr float EPSV = 1e-6f;
constexpr float SCL2 = 0.125f * 1.44269504f;  // (1/sqrt(64)) * log2(e); folded into q

// async global->LDS, 16B per lane. LDS dest = wave-uniform base + lane*16.
__device__ __forceinline__ void async16(void* lds, const void* g) {
  __builtin_amdgcn_global_load_lds((const __attribute__((address_space(1))) void*)g,
                                   (__attribute__((address_space(3))) void*)lds, 16, 0, 0);
}

// BK=32 pair-XOR swizzle: rows are 64B (4 chunks); swizzle unit = row PAIR (8 chunks).
// LDS linear chunk lc <-> (pair p = lc>>3, phys ph = lc&7); global chunk g = ph ^ (p&7),
// global (row, colElems) = (2p + (g>>2), (g&3)*8). Frag read of (row r, kchunk q):
// addr elems = (r>>1)*64 + (((r&1)*4 + q) ^ ((r>>1)&7))*8.  Banks: 2-way (free).
__device__ __forceinline__ int sw32(int r, int q) {
  int p = r >> 1;
  return p * 64 + ((((r & 1) * 4 + q) ^ (p & 7)) * 8);
}

// ---------------- fp32 -> fp16 convert, all three tensors in one launch ----------------
__global__ void cvt_all_kernel(const float* __restrict__ x, const float* __restrict__ wq,
                               const float* __restrict__ wp, f16* __restrict__ xf,
                               f16* __restrict__ wqf, f16* __restrict__ wpf) {
  constexpr int NX4 = BL * DIM / 4;
  constexpr int NW4 = 3 * DIM * DIM / 4;
  int i = blockIdx.x * blockDim.x + threadIdx.x;
  const float4* src;
  f16x4* dst;
  int j;
  if (i < NX4) {
    src = (const float4*)x; dst = (f16x4*)xf; j = i;
  } else if (i < NX4 + NW4) {
    src = (const float4*)wq; dst = (f16x4*)wqf; j = i - NX4;
  } else {
    src = (const float4*)wp; dst = (f16x4*)wpf; j = i - NX4 - NW4;
  }
  float4 a = src[j];
  f16x4 o = {(f16)a.x, (f16)a.y, (f16)a.z, (f16)a.w};
  dst[j] = o;
}

// ============ QKV GEMM: 128x128 tile, BK=32, m97-style single-buffer glLDS ============
__global__ __launch_bounds__(256) void qkv_gemm_kernel(
    const f16* __restrict__ A, const f16* __restrict__ W,
    const float* __restrict__ v0,
    const float* __restrict__ rcos, const float* __restrict__ rsin,
    const float* __restrict__ lamp,
    f16* __restrict__ qb, f16* __restrict__ kb, f16* __restrict__ vbT,
    float* __restrict__ vout) {
  constexpr int K = DIM;
  __shared__ alignas(16) f16 sA[128 * 32];
  __shared__ alignas(16) f16 sB[128 * 32];
  const int tid = threadIdx.x;
  const int w = tid >> 6, lane = tid & 63, ln = lane & 15, quad = lane >> 4;
  const int wm = w >> 1, wn = w & 1;
  const int m0 = blockIdx.y * 128, n0 = blockIdx.x * 128;

  const f16* gA[2];
  const f16* gB[2];
#pragma unroll
  for (int s = 0; s < 2; ++s) {
    int lc = tid + s * 256;
    int p = lc >> 3, g = (lc & 7) ^ (p & 7);
    int r = 2 * p + (g >> 2), ce = (g & 3) * 8;
    gA[s] = A + (size_t)(m0 + r) * K + ce;
    gB[s] = W + (size_t)(n0 + r) * K + ce;
  }

  f32x4 acc[4][4] = {};

  for (int it = 0; it < 32; ++it) {
    const int k0 = it * 32;
#pragma unroll
    for (int s = 0; s < 2; ++s) {
      async16(&sA[(tid + s * 256) * 8], gA[s] + k0);
      async16(&sB[(tid + s * 256) * 8], gB[s] + k0);
    }
    __syncthreads();  // drains glLDS vmcnt
    f16x8 a[4];
#pragma unroll
    for (int mi = 0; mi < 4; ++mi)
      a[mi] = *(const f16x8*)&sA[sw32(wm * 64 + mi * 16 + ln, quad)];
#pragma unroll
    for (int ni = 0; ni < 4; ++ni) {
      f16x8 b = *(const f16x8*)&sB[sw32(wn * 64 + ni * 16 + ln, quad)];
#pragma unroll
      for (int mi = 0; mi < 4; ++mi) acc[mi][ni] = MFMA32(a[mi], b, acc[mi][ni]);
    }
    __syncthreads();  // protect buffer before next stage
  }

  // Epilogue. Wave covers one head (64 cols). C/D: col=ln (ni tile), row=quad*4+rg (mi tile).
  const int nb = n0 + wn * 64;
  const int nsec = nb >> 10;        // 0=q, 1=k, 2=v
  const int h = (nb & 1023) >> 6;   // head

  if (nsec == 2) {
    const float lam = lamp[0];
#pragma unroll
    for (int mi = 0; mi < 4; ++mi) {
#pragma unroll
      for (int rg = 0; rg < 4; ++rg) {
        int row = m0 + wm * 64 + mi * 16 + quad * 4 + rg;
        int b = row >> 11, l = row & 2047;
        size_t base = ((size_t)(b * NH + h) * Ls + l) * HD;
        int key = l & 63;
        // PV B-frag permutation: sidx = quadk*16 + ntk*4 + j -> flash reads b128/lane
        int sidx = ((key >> 2) & 3) * 16 + (key >> 4) * 4 + (key & 3);
        size_t tb = ((size_t)(b * NH + h) * HD) * Ls + (l & ~63) + sidx;
#pragma unroll
        for (int ni = 0; ni < 4; ++ni) {
          int d = ni * 16 + ln;
          float vnew = lam * acc[mi][ni][rg] + (1.0f - lam) * v0[base + d];
          vout[base + d] = vnew;                 // fp32 output #1 (b,h,l,d)
          vbT[tb + (size_t)d * Ls] = (f16)vnew;  // (b,h,d, key-permuted l)
        }
      }
    }
  } else {
    f16* dst = nsec ? kb : qb;
    const float ratio = sqrtf(logf(2048.0f) / logf(1040.0f));
    const float post = nsec ? 1.0f : SCL2;  // fold softmax scale*log2e into q
#pragma unroll
    for (int mi = 0; mi < 4; ++mi) {
#pragma unroll
      for (int rg = 0; rg < 4; ++rg) {
        int row = m0 + wm * 64 + mi * 16 + quad * 4 + rg;
        int b = row >> 11, l = row & 2047;
        float vals[4];
#pragma unroll
        for (int ni = 0; ni < 4; ++ni) vals[ni] = acc[mi][ni][rg];
#pragma unroll
        for (int t = 0; t < 2; ++t) {
          int j = t * 16 + ln;
          float c = rcos[l * 32 + j], s = rsin[l * 32 + j];
          float x1 = vals[t], x2 = vals[t + 2];
          vals[t] = x1 * c + x2 * s;
          vals[t + 2] = -x1 * s + x2 * c;
        }
        if (nsec) {
#pragma unroll
          for (int ni = 0; ni < 4; ++ni) vals[ni] *= ratio;
        }
        float ms = vals[0] * vals[0] + vals[1] * vals[1] + vals[2] * vals[2] + vals[3] * vals[3];
        ms += __shfl_xor(ms, 1);
        ms += __shfl_xor(ms, 2);
        ms += __shfl_xor(ms, 4);
        ms += __shfl_xor(ms, 8);
        float rn = rsqrtf(ms * (1.0f / 64.0f) + EPSV) * post;
        size_t base = ((size_t)(b * NH + h) * Ls + l) * HD;
#pragma unroll
        for (int ni = 0; ni < 4; ++ni) dst[base + ni * 16 + ln] = (f16)(vals[ni] * rn);
      }
    }
  }
}

// ============ Flash attention: kt-split wave groups + all-MFMA32 + rsum-via-ones ============
// 512 threads = 2 groups x 4 waves. Group g owns key range [g*1024, g*1024+1024) with its
// own double-buffered LDS; partial O / rowsum combined through the dead staging LDS at end.
// S^T = K*Q^T (q pre-scaled by SCL2); P stays in registers; PV merged into 16x16x32 MFMAs
// (concat of two P k-tiles is a legal A-frag since the (quad,j)->key labeling matches the
// key-permuted V b128 frags slot-for-slot). Row sums via MFMA(P, ones): lands rowsum at
// C-row quad*4+rg — exactly where the epilogue needs it, no shuffles.
// Block remap: bh-major so all 16 q-tiles of one (b,h) share bx%8 -> same XCD L2 (2MB KV
// working set per XCD, fits 4MB L2).
__global__ __launch_bounds__(512, 4) void flash_kernel(
    const f16* __restrict__ qg, const f16* __restrict__ kg, const f16* __restrict__ vtg,
    f16* __restrict__ ao) {
  __shared__ alignas(16) f16 sK[2][2][64 * 64];   // [group][buf]
  __shared__ alignas(16) f16 sVT[2][2][64 * 64];  // [group][buf] [d][key-permuted]
  const int tid = threadIdx.x;
  const int w = tid >> 6, lane = tid & 63, ln = lane & 15, quad = lane >> 4;
  const int grp = w >> 2, wl = w & 3;  // kt-group, wave-in-group
  const int gt = tid & 255;            // thread id within group (staging)
  const int bx = blockIdx.x;
  const int bh = bx & 31, qt = bx >> 5;  // XCD-major: (b,h) fixed per bx%8 class
  const int h = bh & 15, b = bh >> 4;
  const f16* Qh = qg + (size_t)(b * NH + h) * Ls * HD;
  const f16* Kh = kg + (size_t)(b * NH + h) * Ls * HD;
  const f16* VTh = vtg + (size_t)(b * NH + h) * HD * Ls;
  const int q0 = qt * 128;

  // Q as B-frags straight from global: lane n=ln (q-col), k = kk*32 + quad*8 + j
  // (both groups load the same Q rows — each computes a partial over its key half)
  f16x8 aq[2][2];
#pragma unroll
  for (int st = 0; st < 2; ++st)
#pragma unroll
    for (int kk = 0; kk < 2; ++kk)
      aq[st][kk] = *(const f16x8*)&Qh[(size_t)(q0 + wl * 32 + st * 16 + ln) * HD + kk * 32 + quad * 8];

  f16x8 kr[2], vr[2];
  auto loadKV = [&](int k0) {
#pragma unroll
    for (int s = 0; s < 2; ++s) {
      int ch = gt + s * 256, r = ch >> 3, cg = (ch & 7) * 8;
      kr[s] = *(const f16x8*)&Kh[(size_t)(k0 + r) * HD + cg];
      vr[s] = *(const f16x8*)&VTh[(size_t)r * Ls + k0 + cg];
    }
  };
  auto stageKV = [&](int buf) {
#pragma unroll
    for (int s = 0; s < 2; ++s) {
      int ch = gt + s * 256, r = ch >> 3;
      int po = r * 64 + (((ch & 7) ^ (r & 7)) * 8);
      *(f16x8*)&sK[grp][buf][po] = kr[s];
      *(f16x8*)&sVT[grp][buf][po] = vr[s];
    }
  };

  f32x4 O[2][4] = {};
  f32x4 racc[2] = {};
  const f16x8 onesv = {(f16)1.f, (f16)1.f, (f16)1.f, (f16)1.f,
                       (f16)1.f, (f16)1.f, (f16)1.f, (f16)1.f};
  const f32x4 zc = {};

  const int kbase = grp << 10;  // group key offset
  loadKV(kbase);
  stageKV(0);
  __syncthreads();

  for (int t = 0; t < 16; ++t) {
    const int cur = t & 1;
    if (t < 15) loadKV(kbase + (t + 1) * 64);  // global->reg prefetch across compute

    // S^T + exp in registers -> merged PV A-frags (f16x8 = two 16-key tiles)
    f16x8 pA[2][2];
#pragma unroll
    for (int nt = 0; nt < 4; ++nt) {
      const int r = nt * 16 + ln;  // key row
      const f16x8 kf0 = *(const f16x8*)&sK[grp][cur][r * 64 + ((quad ^ (r & 7)) * 8)];
      const f16x8 kf1 = *(const f16x8*)&sK[grp][cur][r * 64 + (((4 + quad) ^ (r & 7)) * 8)];
#pragma unroll
      for (int st = 0; st < 2; ++st) {
        f32x4 z = MFMA32(kf1, aq[st][1], MFMA32(kf0, aq[st][0], zc));
#pragma unroll
        for (int j = 0; j < 4; ++j)
          pA[st][nt >> 1][(nt & 1) * 4 + j] = (f16)exp2f(z[j]);
      }
    }

    __builtin_amdgcn_s_setprio(1);
    // row sums via MFMA(P, ones): racc[st][rg] = rowsum(q = quad*4+rg), all lanes
#pragma unroll
    for (int st = 0; st < 2; ++st) {
      racc[st] = MFMA32(pA[st][0], onesv, racc[st]);
      racc[st] = MFMA32(pA[st][1], onesv, racc[st]);
    }
    // O += P·V: one b128 V read + one MFMA32 per (dt, nt2, st)
#pragma unroll
    for (int dt = 0; dt < 4; ++dt) {
      const int row = dt * 16 + ln;  // d row
#pragma unroll
      for (int nt2 = 0; nt2 < 2; ++nt2) {
        const f16x8 vf = *(const f16x8*)&sVT[grp][cur][row * 64 + (((quad * 2 + nt2) ^ (row & 7)) * 8)];
#pragma unroll
        for (int st = 0; st < 2; ++st)
          O[st][dt] = MFMA32(pA[st][nt2], vf, O[st][dt]);
      }
    }
    __builtin_amdgcn_s_setprio(0);

    if (t < 15) stageKV(cur ^ 1);  // vmcnt wait lands here, after compute
    __syncthreads();
  }

  // ---- combine the two kt-halves through the (now dead) staging LDS ----
  float* cO = (float*)&sK[0][0][0];   // 128 q x 64 d f32 = 32 KB (all of sK)
  float* cR = (float*)&sVT[0][0][0];  // 128 f32
  if (grp == 1) {
#pragma unroll
    for (int st = 0; st < 2; ++st) {
#pragma unroll
      for (int rg = 0; rg < 4; ++rg) {
        const int ql = wl * 32 + st * 16 + quad * 4 + rg;
#pragma unroll
        for (int dt = 0; dt < 4; ++dt) cO[ql * 64 + dt * 16 + ln] = O[st][dt][rg];
        if (ln == 0) cR[ql] = racc[st][rg];
      }
    }
  }
  __syncthreads();
  if (grp == 0) {
#pragma unroll
    for (int st = 0; st < 2; ++st) {
#pragma unroll
      for (int rg = 0; rg < 4; ++rg) {
        const int ql = wl * 32 + st * 16 + quad * 4 + rg;
        const float inv = 1.0f / (racc[st][rg] + cR[ql]);
        const int q = q0 + ql;
        const size_t orow = ((size_t)b * Ls + q) * DIM + h * HD;
#pragma unroll
        for (int dt = 0; dt < 4; ++dt)
          ao[orow + dt * 16 + ln] = (f16)((O[st][dt][rg] + cO[ql * 64 + dt * 16 + ln]) * inv);
      }
    }
  }
}

// ============ proj GEMM: 64x128 tile, BK=32 m97-style single-buffer glLDS ============
__global__ __launch_bounds__(256) void proj_gemm_kernel(
    const f16* __restrict__ A, const f16* __restrict__ W, float* __restrict__ out) {
  constexpr int K = DIM;
  __shared__ alignas(16) f16 sA[64 * 32];
  __shared__ alignas(16) f16 sB[128 * 32];
  const int tid = threadIdx.x;
  const int w = tid >> 6, lane = tid & 63, ln = lane & 15, quad = lane >> 4;
  const int wm = w >> 1, wn = w & 1;  // wave: 32 rows x 64 cols
  const int m0 = blockIdx.y * 64, n0 = blockIdx.x * 128;

  const f16* gA;  // 256 chunks: 1 per thread
  {
    int p = tid >> 3, g = (tid & 7) ^ (p & 7);
    gA = A + (size_t)(m0 + 2 * p + (g >> 2)) * K + (g & 3) * 8;
  }
  const f16* gB[2];
#pragma unroll
  for (int s = 0; s < 2; ++s) {
    int lc = tid + s * 256;
    int p = lc >> 3, g = (lc & 7) ^ (p & 7);
    gB[s] = W + (size_t)(n0 + 2 * p + (g >> 2)) * K + (g & 3) * 8;
  }

  f32x4 acc[2][4] = {};

  for (int it = 0; it < 32; ++it) {
    const int k0 = it * 32;
    async16(&sA[tid * 8], gA + k0);
#pragma unroll
    for (int s = 0; s < 2; ++s) async16(&sB[(tid + s * 256) * 8], gB[s] + k0);
    __syncthreads();
    f16x8 a[2];
#pragma unroll
    for (int mi = 0; mi < 2; ++mi)
      a[mi] = *(const f16x8*)&sA[sw32(wm * 32 + mi * 16 + ln, quad)];
#pragma unroll
    for (int ni = 0; ni < 4; ++ni) {
      f16x8 b = *(const f16x8*)&sB[sw32(wn * 64 + ni * 16 + ln, quad)];
#pragma unroll
      for (int mi = 0; mi < 2; ++mi) acc[mi][ni] = MFMA32(a[mi], b, acc[mi][ni]);
    }
    __syncthreads();
  }

#pragma unroll
  for (int mi = 0; mi < 2; ++mi) {
#pragma unroll
    for (int rg = 0; rg < 4; ++rg) {
      int row = m0 + wm * 32 + mi * 16 + quad * 4 + rg;
      size_t o = (size_t)row * DIM + n0 + wn * 64;
#pragma unroll
      for (int ni = 0; ni < 4; ++ni) out[o + ni * 16 + ln] = acc[mi][ni][rg];
    }
  }
}

extern "C" void kernel_launch(void* const* d_in, const int* in_sizes, int n_in,
                              void* d_out, int out_size, void* d_ws, size_t ws_size,
                              hipStream_t stream) {
  (void)in_sizes; (void)n_in; (void)out_size; (void)ws_size;
  const float* x = (const float*)d_in[0];
  const float* v0 = (const float*)d_in[1];
  const float* rcos = (const float*)d_in[2];
  const float* rsin = (const float*)d_in[3];
  const float* wqkv = (const float*)d_in[4];
  const float* wproj = (const float*)d_in[5];
  const float* lamp = (const float*)d_in[6];
  float* out = (float*)d_out;
  float* vout = out + (size_t)BL * DIM;  // output #1: blended v, (B,H,L,HD)

  char* p = (char*)d_ws;
  auto take = [&](size_t n) { char* q = p; p += ((n + 255) / 256) * 256; return q; };
  f16* xf = (f16*)take((size_t)BL * DIM * 2);
  f16* wqf = (f16*)take((size_t)3 * DIM * DIM * 2);
  f16* wpf = (f16*)take((size_t)DIM * DIM * 2);
  f16* qb = (f16*)take((size_t)BL * DIM * 2);
  f16* kb = (f16*)take((size_t)BL * DIM * 2);
  f16* vbT = (f16*)take((size_t)BL * DIM * 2);  // (b,h,d, key-permuted l)
  f16* ao = xf;  // x dead after qkv_gemm; reuse (stream-ordered)

  constexpr int NCVT4 = (BL * DIM + 3 * DIM * DIM + DIM * DIM) / 4;
  cvt_all_kernel<<<dim3(NCVT4 / 256), dim3(256), 0, stream>>>(x, wqkv, wproj, xf, wqf, wpf);

  qkv_gemm_kernel<<<dim3(3 * DIM / 128, BL / 128), dim3(256), 0, stream>>>(
      xf, wqf, v0, rcos, rsin, lamp, qb, kb, vbT, vout);

  flash_kernel<<<dim3(Bs * NH * (Ls / 128)), dim3(512), 0, stream>>>(qb, kb, vbT, ao);

  proj_gemm_kernel<<<dim3(DIM / 128, BL / 64), dim3(256), 0, stream>>>(ao, wpf, out);
}